// Round 1
// baseline (421.592 us; speedup 1.0000x reference)
//
#include <hip/hip_runtime.h>

// MoE MLP: B=2,S=2048,H=1024,I=2048,E=8,TOPK=2  -> T=4096 tokens, 8192 entries.
// R7: weights pre-cast to bf16 once (gate/up alias the ent region, which is
// dead until gemm2). Both GEMMs now stage A AND B via XOR-pre-swizzled
// global_load_lds (pure m97 structure) -- removes the fp32 reg-prefetch,
// pkbf VALU work, and the 8-way ds_write bank conflict (1.65e7 cyc).

#define H_DIM 1024
#define I_DIM 2048
#define N_EXP 8
#define N_TOK 4096
#define N_ENT 8192
#define CAP   9216   // 8192 + 8*128 padding capacity (segments padded to 128)

typedef __attribute__((ext_vector_type(8))) short bhalf8;
typedef __attribute__((ext_vector_type(4))) float floatx4;

__device__ __forceinline__ unsigned short f2bf(float f) {
  unsigned int u = __float_as_uint(f);
  u += 0x7fffu + ((u >> 16) & 1u);   // RNE
  return (unsigned short)(u >> 16);
}

__device__ __forceinline__ void ld16(const void* g, void* l) {
  __builtin_amdgcn_global_load_lds(
      (const __attribute__((address_space(1))) unsigned int*)g,
      (__attribute__((address_space(3))) unsigned int*)l, 16, 0, 0);
}

// ---------------- routing ----------------
__global__ __launch_bounds__(256) void route_kernel(
    const int* __restrict__ idx, const float* __restrict__ wts,
    int* __restrict__ perm, float* __restrict__ pw, int* __restrict__ inv,
    int* __restrict__ counts, int* __restrict__ poff)
{
  __shared__ int cnt[N_EXP], cur[N_EXP], off[N_EXP];
  const int t = threadIdx.x;
  if (t < N_EXP) { cnt[t] = 0; cur[t] = 0; }
  __syncthreads();
  for (int i = t; i < N_ENT; i += 256) atomicAdd(&cnt[idx[i] & 7], 1);
  __syncthreads();
  if (t == 0) {
    int o = 0;
    for (int e = 0; e < N_EXP; e++) {
      off[e] = o; counts[e] = cnt[e]; poff[e] = o;
      o += ((cnt[e] + 127) >> 7) << 7;
    }
  }
  __syncthreads();
  for (int i = t; i < N_ENT; i += 256) {
    int e = idx[i] & 7;
    int p = atomicAdd(&cur[e], 1);
    int pos = off[e] + p;
    perm[pos] = i >> 1;
    pw[pos] = wts[i];
    inv[i] = pos;
  }
}

// ---------------- fp32 -> bf16 cast (x: 2048 blocks, each weight: 8192) ----
__global__ __launch_bounds__(256) void cast_kernel(
    const float* __restrict__ s, unsigned short* __restrict__ d)
{
  size_t i = ((size_t)blockIdx.x * 256 + threadIdx.x) * 8;
  const float4* sp = (const float4*)(s + i);
  float4 a = sp[0], b = sp[1];
  bhalf8 o;
  o[0] = (short)f2bf(a.x); o[1] = (short)f2bf(a.y); o[2] = (short)f2bf(a.z); o[3] = (short)f2bf(a.w);
  o[4] = (short)f2bf(b.x); o[5] = (short)f2bf(b.y); o[6] = (short)f2bf(b.z); o[7] = (short)f2bf(b.w);
  *(bhalf8*)(d + i) = o;
}

// ---------------- GEMM1: act = silu(X Wg^T) * (X Wu^T) ----------------
// 512 threads, block tile 256(M) x 64(N) x 2 matrices, BK=64.
// A and B both bf16, staged via swizzled global_load_lds (source pre-swizzled,
// LDS linear). Per wave per K-step: 4 ld16 (A) + 1 (Bg) + 1 (Bu), 32 MFMA.
__global__ __launch_bounds__(512, 4) void gemm1_kernel(
    const unsigned short* __restrict__ xb,
    const unsigned short* __restrict__ gwb,
    const unsigned short* __restrict__ uwb,
    const int* __restrict__ perm,
    const int* __restrict__ counts,
    const int* __restrict__ poff,
    unsigned short* __restrict__ act)
{
  const int e = blockIdx.z;
  const int Ne = counts[e];
  const int mt = blockIdx.y;
  if (mt * 256 >= Ne) return;
  const int NeR = ((Ne + 127) >> 7) << 7;
  const int base = poff[e];
  const int n0 = blockIdx.x * 64;

  __shared__ __align__(16) unsigned short As[256 * 64];   // 32 KB (swizzled)
  __shared__ __align__(16) unsigned short Bgs[64 * 64];   //  8 KB (swizzled)
  __shared__ __align__(16) unsigned short Bus[64 * 64];   //  8 KB (swizzled)

  const int tid = threadIdx.x;
  const int lane = tid & 63;
  const int w = tid >> 6;          // 0..7
  const int wmi = w >> 1;          // 0..3 (M)
  const int wnj = w & 1;           // 0..1 (N)
  const int i3 = lane >> 3, i7 = lane & 7;
  const int swc = (i7 ^ i3) * 8;   // pre-swizzled k-chunk offset

  // A: 4 ld16/wave -> 32 rows
  const unsigned short* pA[4]; unsigned short* lA[4];
#pragma unroll
  for (int t = 0; t < 4; t++) {
    int rloc = w * 32 + t * 8 + i3;
    int rr = mt * 256 + rloc; rr = rr < Ne ? rr : Ne - 1;
    pA[t] = xb + (size_t)perm[base + rr] * H_DIM + swc;
    lA[t] = &As[(w * 32 + t * 8) * 64];
  }
  // B: 1 ld16/wave/matrix -> 8 rows each (rows n0 + w*8 + i3)
  const size_t wb = (size_t)e * (I_DIM * H_DIM) + (size_t)(n0 + w * 8 + i3) * H_DIM + swc;
  const unsigned short* pBg = gwb + wb;
  const unsigned short* pBu = uwb + wb;
  unsigned short* lBg = &Bgs[(w * 8) * 64];
  unsigned short* lBu = &Bus[(w * 8) * 64];

  floatx4 zero = {0.f, 0.f, 0.f, 0.f};
  floatx4 accg[4][2], accu[4][2];
#pragma unroll
  for (int i = 0; i < 4; i++)
#pragma unroll
    for (int j = 0; j < 2; j++) { accg[i][j] = zero; accu[i][j] = zero; }

  const int quad = lane >> 4, lm = lane & 15;
  const int s7 = lm & 7;

  for (int k0 = 0; k0 < H_DIM; k0 += 64) {
    __syncthreads();
#pragma unroll
    for (int t = 0; t < 4; t++) ld16(pA[t] + k0, lA[t]);
    ld16(pBg + k0, lBg);
    ld16(pBu + k0, lBu);
    __syncthreads();
#pragma unroll
    for (int kk = 0; kk < 2; kk++) {
      const int kq = kk * 4 + quad;
      const int ko = (kq ^ s7) * 8;
      bhalf8 a[4], bg[2], bu[2];
#pragma unroll
      for (int i = 0; i < 4; i++)
        a[i] = *(const bhalf8*)&As[(wmi * 64 + i * 16 + lm) * 64 + ko];
#pragma unroll
      for (int j = 0; j < 2; j++) {
        bg[j] = *(const bhalf8*)&Bgs[(wnj * 32 + j * 16 + lm) * 64 + ko];
        bu[j] = *(const bhalf8*)&Bus[(wnj * 32 + j * 16 + lm) * 64 + ko];
      }
#pragma unroll
      for (int i = 0; i < 4; i++)
#pragma unroll
        for (int j = 0; j < 2; j++) {
          accg[i][j] = __builtin_amdgcn_mfma_f32_16x16x32_bf16(a[i], bg[j], accg[i][j], 0, 0, 0);
          accu[i][j] = __builtin_amdgcn_mfma_f32_16x16x32_bf16(a[i], bu[j], accu[i][j], 0, 0, 0);
        }
    }
  }

#pragma unroll
  for (int i = 0; i < 4; i++) {
#pragma unroll
    for (int r = 0; r < 4; r++) {
      int row = mt * 256 + wmi * 64 + i * 16 + quad * 4 + r;
      if (row < NeR) {
        size_t rowoff = (size_t)(base + row) * I_DIM;
#pragma unroll
        for (int j = 0; j < 2; j++) {
          int col = n0 + wnj * 32 + j * 16 + lm;
          float g = accg[i][j][r];
          float u = accu[i][j][r];
          float h = (g / (1.f + __expf(-g))) * u;
          act[rowoff + col] = (unsigned short)f2bf(h);
        }
      }
    }
  }
}

// ---------------- GEMM2: ent[half][row] = pw[row]*(act x down^T over K-half) --
// 512 threads, block tile 256x128, BK=64, split-K=2: blockIdx.x = (kh<<3)|nx.
// A and B both bf16 via swizzled global_load_lds.
__global__ __launch_bounds__(512, 4) void gemm2_kernel(
    const unsigned short* __restrict__ act,
    const unsigned short* __restrict__ dwb,
    const float* __restrict__ pw,
    const int* __restrict__ counts,
    const int* __restrict__ poff,
    float* __restrict__ ent)
{
  const int e = blockIdx.z;
  const int Ne = counts[e];
  const int mt = blockIdx.y;
  if (mt * 256 >= Ne) return;
  const int NeR = ((Ne + 127) >> 7) << 7;
  const int base = poff[e];
  const int n0 = (blockIdx.x & 7) * 128;
  const int k_lo = (blockIdx.x >> 3) * (I_DIM / 2);

  __shared__ __align__(16) unsigned short As[256 * 64];   // 32 KB (swizzled)
  __shared__ __align__(16) unsigned short Bs[128 * 64];   // 16 KB (swizzled)

  const int tid = threadIdx.x;
  const int lane = tid & 63;
  const int w = tid >> 6;
  const int wmi = w >> 1, wnj = w & 1;
  const int i3 = lane >> 3, i7 = lane & 7;
  const int swc = (i7 ^ i3) * 8;

  const unsigned short* pA[4]; unsigned short* lA[4];
#pragma unroll
  for (int t = 0; t < 4; t++) {
    int rloc = w * 32 + t * 8 + i3;
    int rr = mt * 256 + rloc; rr = rr < NeR ? rr : NeR - 1;
    pA[t] = act + (size_t)(base + rr) * I_DIM + k_lo + swc;
    lA[t] = &As[(w * 32 + t * 8) * 64];
  }
  // B: 2 ld16/wave -> rows w*16 + {0,8} + i3
  const unsigned short* pB[2]; unsigned short* lB[2];
#pragma unroll
  for (int t = 0; t < 2; t++) {
    int rloc = w * 16 + t * 8 + i3;
    pB[t] = dwb + (size_t)e * (H_DIM * I_DIM) + (size_t)(n0 + rloc) * I_DIM + k_lo + swc;
    lB[t] = &Bs[(w * 16 + t * 8) * 64];
  }

  floatx4 zero = {0.f, 0.f, 0.f, 0.f};
  floatx4 acc[4][4];
#pragma unroll
  for (int i = 0; i < 4; i++)
#pragma unroll
    for (int j = 0; j < 4; j++) acc[i][j] = zero;

  const int quad = lane >> 4, lm = lane & 15;
  const int s7 = lm & 7;

  for (int k0 = 0; k0 < I_DIM / 2; k0 += 64) {
    __syncthreads();
#pragma unroll
    for (int t = 0; t < 4; t++) ld16(pA[t] + k0, lA[t]);
#pragma unroll
    for (int t = 0; t < 2; t++) ld16(pB[t] + k0, lB[t]);
    __syncthreads();
#pragma unroll
    for (int kk = 0; kk < 2; kk++) {
      const int kq = kk * 4 + quad;
      const int ko = (kq ^ s7) * 8;
      bhalf8 a[4], b[4];
#pragma unroll
      for (int i = 0; i < 4; i++)
        a[i] = *(const bhalf8*)&As[(wmi * 64 + i * 16 + lm) * 64 + ko];
#pragma unroll
      for (int j = 0; j < 4; j++)
        b[j] = *(const bhalf8*)&Bs[(wnj * 64 + j * 16 + lm) * 64 + ko];
#pragma unroll
      for (int i = 0; i < 4; i++)
#pragma unroll
        for (int j = 0; j < 4; j++)
          acc[i][j] = __builtin_amdgcn_mfma_f32_16x16x32_bf16(a[i], b[j], acc[i][j], 0, 0, 0);
    }
  }

  float* enth = ent + (size_t)(blockIdx.x >> 3) * CAP * H_DIM;
#pragma unroll
  for (int i = 0; i < 4; i++) {
#pragma unroll
    for (int r = 0; r < 4; r++) {
      int row = mt * 256 + wmi * 64 + i * 16 + quad * 4 + r;
      if (row < Ne) {
        float wt = pw[base + row];
        float* orow = enth + (size_t)(base + row) * H_DIM;
#pragma unroll
        for (int j = 0; j < 4; j++) {
          int col = n0 + wnj * 64 + j * 16 + lm;
          orow[col] = wt * acc[i][j][r];
        }
      }
    }
  }
}

// ---------------- combine ----------------
__global__ __launch_bounds__(256) void combine_kernel(
    const float* __restrict__ ent, const int* __restrict__ inv,
    float* __restrict__ out)
{
  const int t = blockIdx.x;
  const int p0 = inv[2 * t], p1 = inv[2 * t + 1];
  const float4* r0 = (const float4*)(ent + (size_t)p0 * H_DIM);
  const float4* r1 = (const float4*)(ent + (size_t)p1 * H_DIM);
  const float4* r2 = (const float4*)(ent + (size_t)(CAP + p0) * H_DIM);
  const float4* r3 = (const float4*)(ent + (size_t)(CAP + p1) * H_DIM);
  float4 a = r0[threadIdx.x], b = r1[threadIdx.x];
  float4 c = r2[threadIdx.x], d = r3[threadIdx.x];
  float4 o = {a.x + b.x + c.x + d.x, a.y + b.y + c.y + d.y,
              a.z + b.z + c.z + d.z, a.w + b.w + c.w + d.w};
  ((float4*)(out + (size_t)t * H_DIM))[threadIdx.x] = o;
}

extern "C" void kernel_launch(void* const* d_in, const int* in_sizes, int n_in,
                              void* d_out, int out_size, void* d_ws, size_t ws_size,
                              hipStream_t stream) {
  const float* x    = (const float*)d_in[0];
  const int*   idx  = (const int*)d_in[1];
  const float* wts  = (const float*)d_in[2];
  const float* gate = (const float*)d_in[3];
  const float* up   = (const float*)d_in[4];
  const float* down = (const float*)d_in[5];
  float* out = (float*)d_out;
  char* ws = (char*)d_ws;

  // workspace layout (bytes)
  float*          ent = (float*)(ws + 0);                   // 75,497,472 (2*CAP*H*4)
  // gate/up bf16 ALIAS the ent region: gemm1 consumes them before gemm2
  // writes ent (stream-serial), combine only reads rows gemm2 wrote.
  unsigned short* gb  = (unsigned short*)(ws + 0);          // 33,554,432
  unsigned short* ub  = (unsigned short*)(ws + 33554432);   // 33,554,432 (< 75.5MB)
  unsigned short* act = (unsigned short*)(ws + 75497472);   // 37,748,736 (CAP*I*2)
  unsigned short* xb  = (unsigned short*)(ws + 113246208);  //  8,388,608
  unsigned short* db  = (unsigned short*)(ws + 121634816);  // 33,554,432 (E*H*I*2)
  int*   perm   = (int*)(ws + 155189248);                   // 36,864
  float* pw     = (float*)(ws + 155226112);                 // 36,864
  int*   inv    = (int*)(ws + 155262976);                   // 32,768
  int*   counts = (int*)(ws + 155295744);                   // 32
  int*   poff   = (int*)(ws + 155295808);                   // 32  (total 155,295,840)

  route_kernel<<<1, 256, 0, stream>>>(idx, wts, perm, pw, inv, counts, poff);

  cast_kernel<<<(N_TOK * H_DIM) / (256 * 8), 256, 0, stream>>>(x, xb);
  cast_kernel<<<(N_EXP * I_DIM * H_DIM) / (256 * 8), 256, 0, stream>>>(gate, gb);
  cast_kernel<<<(N_EXP * I_DIM * H_DIM) / (256 * 8), 256, 0, stream>>>(up, ub);
  cast_kernel<<<(N_EXP * H_DIM * I_DIM) / (256 * 8), 256, 0, stream>>>(down, db);

  gemm1_kernel<<<dim3(I_DIM / 64, 32, N_EXP), 512, 0, stream>>>(
      xb, gb, ub, perm, counts, poff, act);

  gemm2_kernel<<<dim3(16, 32, N_EXP), 512, 0, stream>>>(
      act, db, pw, counts, poff, ent);

  combine_kernel<<<N_TOK, 256, 0, stream>>>(ent, inv, out);
}

// Round 2
// 383.875 us; speedup vs baseline: 1.0983x; 1.0983x over previous
//
#include <hip/hip_runtime.h>

// MoE MLP: B=2,S=2048,H=1024,I=2048,E=8,TOPK=2  -> T=4096 tokens, 8192 entries.
// R8: fp32->bf16 weight cast fused back into GEMM B-staging (reg prefetch ->
// pkbf -> ds_write) but writing the R7 XOR-swizzled layout row*128B +
// (chunk^(row&7))*16B, which is bank-conflict-free (R6's (chunk*64+row)*16B
// was an 8-way conflict = 1.65e7 cyc). A-operands keep swizzled
// global_load_lds. route merged into the x-cast kernel. 8 launches -> 4.

#define H_DIM 1024
#define I_DIM 2048
#define N_EXP 8
#define N_TOK 4096
#define N_ENT 8192
#define CAP   9216   // 8192 + 8*128 padding capacity (segments padded to 128)

typedef __attribute__((ext_vector_type(8))) short bhalf8;
typedef __attribute__((ext_vector_type(4))) float floatx4;

__device__ __forceinline__ unsigned short f2bf(float f) {
  unsigned int u = __float_as_uint(f);
  u += 0x7fffu + ((u >> 16) & 1u);   // RNE
  return (unsigned short)(u >> 16);
}

// pack two fp32 -> bf16x2 (round-half-up), one v_perm_b32
__device__ __forceinline__ unsigned int pkbf(float a, float b) {
  unsigned int ua = __float_as_uint(a) + 0x8000u;
  unsigned int ub = __float_as_uint(b) + 0x8000u;
  return __builtin_amdgcn_perm(ub, ua, 0x07060302u);  // low16=a_hi, high16=b_hi
}

__device__ __forceinline__ void ld16(const void* g, void* l) {
  __builtin_amdgcn_global_load_lds(
      (const __attribute__((address_space(1))) unsigned int*)g,
      (__attribute__((address_space(3))) unsigned int*)l, 16, 0, 0);
}

// ---------------- prep: x cast (blocks 0..2047) + routing (block 2048) ------
__global__ __launch_bounds__(256) void prep_kernel(
    const float* __restrict__ x, unsigned short* __restrict__ xb,
    const int* __restrict__ idx, const float* __restrict__ wts,
    int* __restrict__ perm, float* __restrict__ pw, int* __restrict__ inv,
    int* __restrict__ counts, int* __restrict__ poff)
{
  __shared__ int cnt[N_EXP], cur[N_EXP], off[N_EXP];
  const int t = threadIdx.x;
  if (blockIdx.x < (N_TOK * H_DIM) / (256 * 8)) {
    size_t i = ((size_t)blockIdx.x * 256 + t) * 8;
    const float4* sp = (const float4*)(x + i);
    float4 a = sp[0], b = sp[1];
    bhalf8 o;
    o[0] = (short)f2bf(a.x); o[1] = (short)f2bf(a.y); o[2] = (short)f2bf(a.z); o[3] = (short)f2bf(a.w);
    o[4] = (short)f2bf(b.x); o[5] = (short)f2bf(b.y); o[6] = (short)f2bf(b.z); o[7] = (short)f2bf(b.w);
    *(bhalf8*)(xb + i) = o;
    return;
  }
  // routing block
  if (t < N_EXP) { cnt[t] = 0; cur[t] = 0; }
  __syncthreads();
  for (int i = t; i < N_ENT; i += 256) atomicAdd(&cnt[idx[i] & 7], 1);
  __syncthreads();
  if (t == 0) {
    int o = 0;
    for (int e = 0; e < N_EXP; e++) {
      off[e] = o; counts[e] = cnt[e]; poff[e] = o;
      o += ((cnt[e] + 127) >> 7) << 7;
    }
  }
  __syncthreads();
  for (int i = t; i < N_ENT; i += 256) {
    int e = idx[i] & 7;
    int p = atomicAdd(&cur[e], 1);
    int pos = off[e] + p;
    perm[pos] = i >> 1;
    pw[pos] = wts[i];
    inv[i] = pos;
  }
}

// ---------------- GEMM1: act = silu(X Wg^T) * (X Wu^T) ----------------
// 512 threads, block tile 256(M) x 64(N) x 2 matrices, BK=64.
// A: bf16 swizzled global_load_lds. B: fp32 -> VGPR prefetch -> pkbf ->
// swizzled ds_write_b128 (cell (row,c) at row*128B + (c^(row&7))*16B,
// conflict-free). MFMA read side identical to R7.
__global__ __launch_bounds__(512, 4) void gemm1_kernel(
    const unsigned short* __restrict__ xb,
    const float* __restrict__ gw,
    const float* __restrict__ uw,
    const int* __restrict__ perm,
    const int* __restrict__ counts,
    const int* __restrict__ poff,
    unsigned short* __restrict__ act)
{
  const int e = blockIdx.z;
  const int Ne = counts[e];
  const int mt = blockIdx.y;
  if (mt * 256 >= Ne) return;
  const int NeR = ((Ne + 127) >> 7) << 7;
  const int base = poff[e];
  const int n0 = blockIdx.x * 64;

  __shared__ __align__(16) unsigned short As[256 * 64];   // 32 KB (swizzled)
  __shared__ __align__(16) unsigned short Bgs[64 * 64];   //  8 KB (swizzled)
  __shared__ __align__(16) unsigned short Bus[64 * 64];   //  8 KB (swizzled)

  const int tid = threadIdx.x;
  const int lane = tid & 63;
  const int w = tid >> 6;          // 0..7
  const int wmi = w >> 1;          // 0..3 (M)
  const int wnj = w & 1;           // 0..1 (N)
  const int i3 = lane >> 3, i7 = lane & 7;
  const int swc = (i7 ^ i3) * 8;   // pre-swizzled k-chunk offset

  // A: 4 ld16/wave -> 32 rows
  const unsigned short* pA[4]; unsigned short* lA[4];
#pragma unroll
  for (int t = 0; t < 4; t++) {
    int rloc = w * 32 + t * 8 + i3;
    int rr = mt * 256 + rloc; rr = rr < Ne ? rr : Ne - 1;
    pA[t] = xb + (size_t)perm[base + rr] * H_DIM + swc;
    lA[t] = &As[(w * 32 + t * 8) * 64];
  }
  // B: 1 cell per thread per matrix: row nloc = w*8+i3, chunk i7 (8 fp32)
  const int nlocB = w * 8 + i3;
  const size_t wb = (size_t)e * (I_DIM * H_DIM) + (size_t)(n0 + nlocB) * H_DIM + i7 * 8;
  const float* pg = gw + wb;
  const float* pu = uw + wb;
  // swizzled LDS destination: row nlocB, chunk i7 -> chunk slot i7^(nlocB&7)=i7^i3
  unsigned short* lBg = &Bgs[nlocB * 64 + ((i7 ^ i3) * 8)];
  unsigned short* lBu = &Bus[nlocB * 64 + ((i7 ^ i3) * 8)];

  floatx4 zero = {0.f, 0.f, 0.f, 0.f};
  floatx4 accg[4][2], accu[4][2];
#pragma unroll
  for (int i = 0; i < 4; i++)
#pragma unroll
    for (int j = 0; j < 2; j++) { accg[i][j] = zero; accu[i][j] = zero; }

  const int quad = lane >> 4, lm = lane & 15;
  const int s7 = lm & 7;

  // prefetch B for k0=0
  float4 g0 = *(const float4*)(pg);
  float4 g1 = *(const float4*)(pg + 4);
  float4 u0 = *(const float4*)(pu);
  float4 u1 = *(const float4*)(pu + 4);

  for (int k0 = 0; k0 < H_DIM; k0 += 64) {
    __syncthreads();
#pragma unroll
    for (int t = 0; t < 4; t++) ld16(pA[t] + k0, lA[t]);
    *(uint4*)lBg = make_uint4(pkbf(g0.x, g0.y), pkbf(g0.z, g0.w),
                              pkbf(g1.x, g1.y), pkbf(g1.z, g1.w));
    *(uint4*)lBu = make_uint4(pkbf(u0.x, u0.y), pkbf(u0.z, u0.w),
                              pkbf(u1.x, u1.y), pkbf(u1.z, u1.w));
    __syncthreads();
    if (k0 + 64 < H_DIM) {   // prefetch next B tile; overlaps with MFMA below
      g0 = *(const float4*)(pg + k0 + 64);
      g1 = *(const float4*)(pg + k0 + 68);
      u0 = *(const float4*)(pu + k0 + 64);
      u1 = *(const float4*)(pu + k0 + 68);
    }
#pragma unroll
    for (int kk = 0; kk < 2; kk++) {
      const int kq = kk * 4 + quad;
      const int ko = (kq ^ s7) * 8;
      bhalf8 a[4], bg[2], bu[2];
#pragma unroll
      for (int i = 0; i < 4; i++)
        a[i] = *(const bhalf8*)&As[(wmi * 64 + i * 16 + lm) * 64 + ko];
#pragma unroll
      for (int j = 0; j < 2; j++) {
        bg[j] = *(const bhalf8*)&Bgs[(wnj * 32 + j * 16 + lm) * 64 + ko];
        bu[j] = *(const bhalf8*)&Bus[(wnj * 32 + j * 16 + lm) * 64 + ko];
      }
#pragma unroll
      for (int i = 0; i < 4; i++)
#pragma unroll
        for (int j = 0; j < 2; j++) {
          accg[i][j] = __builtin_amdgcn_mfma_f32_16x16x32_bf16(a[i], bg[j], accg[i][j], 0, 0, 0);
          accu[i][j] = __builtin_amdgcn_mfma_f32_16x16x32_bf16(a[i], bu[j], accu[i][j], 0, 0, 0);
        }
    }
  }

#pragma unroll
  for (int i = 0; i < 4; i++) {
#pragma unroll
    for (int r = 0; r < 4; r++) {
      int row = mt * 256 + wmi * 64 + i * 16 + quad * 4 + r;
      if (row < NeR) {
        size_t rowoff = (size_t)(base + row) * I_DIM;
#pragma unroll
        for (int j = 0; j < 2; j++) {
          int col = n0 + wnj * 32 + j * 16 + lm;
          float g = accg[i][j][r];
          float u = accu[i][j][r];
          float h = (g / (1.f + __expf(-g))) * u;
          act[rowoff + col] = (unsigned short)f2bf(h);
        }
      }
    }
  }
}

// ---------------- GEMM2: ent[half][row] = pw[row]*(act x down^T over K-half) --
// 512 threads, block tile 256x128, BK=64, split-K=2: blockIdx.x = (kh<<3)|nx.
// A: bf16 swizzled ld16 from act. B: fp32 down -> reg prefetch -> swizzled
// ds_write (conflict-free layout as gemm1).
__global__ __launch_bounds__(512, 4) void gemm2_kernel(
    const unsigned short* __restrict__ act,
    const float* __restrict__ dw,
    const float* __restrict__ pw,
    const int* __restrict__ counts,
    const int* __restrict__ poff,
    float* __restrict__ ent)
{
  const int e = blockIdx.z;
  const int Ne = counts[e];
  const int mt = blockIdx.y;
  if (mt * 256 >= Ne) return;
  const int NeR = ((Ne + 127) >> 7) << 7;
  const int base = poff[e];
  const int n0 = (blockIdx.x & 7) * 128;
  const int k_lo = (blockIdx.x >> 3) * (I_DIM / 2);

  __shared__ __align__(16) unsigned short As[256 * 64];   // 32 KB (swizzled)
  __shared__ __align__(16) unsigned short Bs[128 * 64];   // 16 KB (swizzled)

  const int tid = threadIdx.x;
  const int lane = tid & 63;
  const int w = tid >> 6;
  const int wmi = w >> 1, wnj = w & 1;
  const int i3 = lane >> 3, i7 = lane & 7;
  const int swc = (i7 ^ i3) * 8;

  const unsigned short* pA[4]; unsigned short* lA[4];
#pragma unroll
  for (int t = 0; t < 4; t++) {
    int rloc = w * 32 + t * 8 + i3;
    int rr = mt * 256 + rloc; rr = rr < NeR ? rr : NeR - 1;
    pA[t] = act + (size_t)(base + rr) * I_DIM + k_lo + swc;
    lA[t] = &As[(w * 32 + t * 8) * 64];
  }
  // B: 2 cells/thread: rows w*16+{0,8}+i3, chunk i7
  const float* pB[2]; unsigned short* lB[2];
#pragma unroll
  for (int t = 0; t < 2; t++) {
    int rloc = w * 16 + t * 8 + i3;
    pB[t] = dw + (size_t)e * (H_DIM * I_DIM) + (size_t)(n0 + rloc) * I_DIM + k_lo + i7 * 8;
    lB[t] = &Bs[rloc * 64 + ((i7 ^ i3) * 8)];   // rloc&7 == i3
  }

  floatx4 zero = {0.f, 0.f, 0.f, 0.f};
  floatx4 acc[4][4];
#pragma unroll
  for (int i = 0; i < 4; i++)
#pragma unroll
    for (int j = 0; j < 4; j++) acc[i][j] = zero;

  const int quad = lane >> 4, lm = lane & 15;
  const int s7 = lm & 7;

  float4 b00 = *(const float4*)(pB[0]);
  float4 b01 = *(const float4*)(pB[0] + 4);
  float4 b10 = *(const float4*)(pB[1]);
  float4 b11 = *(const float4*)(pB[1] + 4);

  for (int k0 = 0; k0 < I_DIM / 2; k0 += 64) {
    __syncthreads();
#pragma unroll
    for (int t = 0; t < 4; t++) ld16(pA[t] + k0, lA[t]);
    *(uint4*)lB[0] = make_uint4(pkbf(b00.x, b00.y), pkbf(b00.z, b00.w),
                                pkbf(b01.x, b01.y), pkbf(b01.z, b01.w));
    *(uint4*)lB[1] = make_uint4(pkbf(b10.x, b10.y), pkbf(b10.z, b10.w),
                                pkbf(b11.x, b11.y), pkbf(b11.z, b11.w));
    __syncthreads();
    if (k0 + 64 < I_DIM / 2) {
      b00 = *(const float4*)(pB[0] + k0 + 64);
      b01 = *(const float4*)(pB[0] + k0 + 68);
      b10 = *(const float4*)(pB[1] + k0 + 64);
      b11 = *(const float4*)(pB[1] + k0 + 68);
    }
#pragma unroll
    for (int kk = 0; kk < 2; kk++) {
      const int kq = kk * 4 + quad;
      const int ko = (kq ^ s7) * 8;
      bhalf8 a[4], b[4];
#pragma unroll
      for (int i = 0; i < 4; i++)
        a[i] = *(const bhalf8*)&As[(wmi * 64 + i * 16 + lm) * 64 + ko];
#pragma unroll
      for (int j = 0; j < 4; j++)
        b[j] = *(const bhalf8*)&Bs[(wnj * 64 + j * 16 + lm) * 64 + ko];
#pragma unroll
      for (int i = 0; i < 4; i++)
#pragma unroll
        for (int j = 0; j < 4; j++)
          acc[i][j] = __builtin_amdgcn_mfma_f32_16x16x32_bf16(a[i], b[j], acc[i][j], 0, 0, 0);
    }
  }

  float* enth = ent + (size_t)(blockIdx.x >> 3) * CAP * H_DIM;
#pragma unroll
  for (int i = 0; i < 4; i++) {
#pragma unroll
    for (int r = 0; r < 4; r++) {
      int row = mt * 256 + wmi * 64 + i * 16 + quad * 4 + r;
      if (row < Ne) {
        float wt = pw[base + row];
        float* orow = enth + (size_t)(base + row) * H_DIM;
#pragma unroll
        for (int j = 0; j < 4; j++) {
          int col = n0 + wnj * 64 + j * 16 + lm;
          orow[col] = wt * acc[i][j][r];
        }
      }
    }
  }
}

// ---------------- combine ----------------
__global__ __launch_bounds__(256) void combine_kernel(
    const float* __restrict__ ent, const int* __restrict__ inv,
    float* __restrict__ out)
{
  const int t = blockIdx.x;
  const int p0 = inv[2 * t], p1 = inv[2 * t + 1];
  const float4* r0 = (const float4*)(ent + (size_t)p0 * H_DIM);
  const float4* r1 = (const float4*)(ent + (size_t)p1 * H_DIM);
  const float4* r2 = (const float4*)(ent + (size_t)(CAP + p0) * H_DIM);
  const float4* r3 = (const float4*)(ent + (size_t)(CAP + p1) * H_DIM);
  float4 a = r0[threadIdx.x], b = r1[threadIdx.x];
  float4 c = r2[threadIdx.x], d = r3[threadIdx.x];
  float4 o = {a.x + b.x + c.x + d.x, a.y + b.y + c.y + d.y,
              a.z + b.z + c.z + d.z, a.w + b.w + c.w + d.w};
  ((float4*)(out + (size_t)t * H_DIM))[threadIdx.x] = o;
}

extern "C" void kernel_launch(void* const* d_in, const int* in_sizes, int n_in,
                              void* d_out, int out_size, void* d_ws, size_t ws_size,
                              hipStream_t stream) {
  const float* x    = (const float*)d_in[0];
  const int*   idx  = (const int*)d_in[1];
  const float* wts  = (const float*)d_in[2];
  const float* gate = (const float*)d_in[3];
  const float* up   = (const float*)d_in[4];
  const float* down = (const float*)d_in[5];
  float* out = (float*)d_out;
  char* ws = (char*)d_ws;

  // workspace layout (bytes)
  float*          ent = (float*)(ws + 0);                   // 75,497,472 (2*CAP*H*4)
  unsigned short* act = (unsigned short*)(ws + 75497472);   // 37,748,736 (CAP*I*2)
  unsigned short* xb  = (unsigned short*)(ws + 113246208);  //  8,388,608
  int*   perm   = (int*)(ws + 121634816);                   // 36,864
  float* pw     = (float*)(ws + 121671680);                 // 36,864
  int*   inv    = (int*)(ws + 121708544);                   // 32,768
  int*   counts = (int*)(ws + 121741312);                   // 32
  int*   poff   = (int*)(ws + 121741376);                   // 32

  prep_kernel<<<(N_TOK * H_DIM) / (256 * 8) + 1, 256, 0, stream>>>(
      x, xb, idx, wts, perm, pw, inv, counts, poff);

  gemm1_kernel<<<dim3(I_DIM / 64, 32, N_EXP), 512, 0, stream>>>(
      xb, gate, up, perm, counts, poff, act);

  gemm2_kernel<<<dim3(16, 32, N_EXP), 512, 0, stream>>>(
      act, down, pw, counts, poff, ent);

  combine_kernel<<<N_TOK, 256, 0, stream>>>(ent, inv, out);
}